// Round 9
// baseline (192.153 us; speedup 1.0000x reference)
//
#include <hip/hip_runtime.h>
#include <hip/hip_bf16.h>

#define L_SEQ 4096
#define E_DIM 512
#define NHEAD 8
#define DHEAD 64
#define NBATCH 4
#define NROWS (NBATCH * L_SEQ)   // 16384

typedef short bf16x8 __attribute__((ext_vector_type(8)));
typedef float f32x4 __attribute__((ext_vector_type(4)));

__device__ __forceinline__ float bf2f(ushort u) {
    union { float f; unsigned int i; } x;
    x.i = ((unsigned int)u) << 16;
    return x.f;
}
__device__ __forceinline__ ushort f2bf(float f) {
    unsigned int u = __float_as_uint(f);
    unsigned int r = 0x7fffu + ((u >> 16) & 1u);
    u += r;
    return (ushort)(u >> 16);
}

// ---------------- weights conversion + sin/cos tables ----------------
__global__ __launch_bounds__(256) void convert_w_kernel(
    const float* __restrict__ w0, const float* __restrict__ w1,
    const float* __restrict__ w2, const float* __restrict__ w3,
    ushort* __restrict__ o0, ushort* __restrict__ o1,
    ushort* __restrict__ o2, ushort* __restrict__ o3,
    float* __restrict__ sintab, float* __restrict__ costab)
{
    const int tid = threadIdx.x;
    const int y = blockIdx.y;
    if (y == 4) {
        const int l = blockIdx.x * 256 + tid;
        if (blockIdx.x < 16) {
            const float ang = (float)(l + 1) * (1.5707963267948966f / (float)L_SEQ);
            sintab[l] = sinf(ang);
            costab[l] = cosf(ang);
        }
        return;
    }
    const float* in = (y == 0) ? w0 : (y == 1) ? w1 : (y == 2) ? w2 : w3;
    ushort* out = (y == 0) ? o0 : (y == 1) ? o1 : (y == 2) ? o2 : o3;
    const int i = blockIdx.x * 256 + tid;
    float4 f = reinterpret_cast<const float4*>(in)[i];
    ushort4 o;
    o.x = f2bf(f.x); o.y = f2bf(f.y); o.z = f2bf(f.z); o.w = f2bf(f.w);
    reinterpret_cast<ushort4*>(out)[i] = o;
}

// ---------------- QKV GEMM, kv_kernel-style: no LDS staging, no main-loop barriers ---
// grid (128, 4), 256 thr (2x2 waves, wave-tile 64x64). Block does modes 0,1,2 at
// fixed (rowBase, colBase). A = x (f32, repacked in-register); B = bf16 weights.
// mode 0 (Q): relu -> qb bf16 [l][e]
// mode 1 (K): relu -> kT[bh][k][l] via LDS transpose epilogue
// mode 2 (V): -> vT[bh][d][l] via LDS transpose epilogue
__global__ __launch_bounds__(256) void qkv2_kernel(
    const float* __restrict__ x,
    const ushort* __restrict__ wq, const ushort* __restrict__ wk, const ushort* __restrict__ wv,
    const float* __restrict__ bq, const float* __restrict__ bk, const float* __restrict__ bv,
    ushort* __restrict__ qb, ushort* __restrict__ kT, ushort* __restrict__ vT)
{
    __shared__ ushort TS[128 * 136];   // transpose staging (epilogue only), 34.8KB

    const int tid = threadIdx.x;
    const int lane = tid & 63;
    const int wid = tid >> 6;
    const int wm = wid >> 1, wn = wid & 1;
    const int rowBase = blockIdx.x * 128;
    const int colBase = blockIdx.y * 128;
    const int fr = lane & 15;
    const int g = lane >> 4;

    const ushort* Wsel[3] = {wq, wk, wv};
    const float* Bsel[3] = {bq, bk, bv};

    const float* xrow[4];
#pragma unroll
    for (int m = 0; m < 4; ++m)
        xrow[m] = &x[(size_t)(rowBase + wm * 64 + m * 16 + fr) * E_DIM + g * 8];
    const ushort* wrow_off[4];

    const int b = rowBase >> 12;
    const int lloc = rowBase & (L_SEQ - 1);

    for (int mode = 0; mode < 3; ++mode) {
        const ushort* __restrict__ W = Wsel[mode];
        const float* __restrict__ bias = Bsel[mode];
#pragma unroll
        for (int n = 0; n < 4; ++n)
            wrow_off[n] = &W[(size_t)(colBase + wn * 64 + n * 16 + fr) * E_DIM + g * 8];

        f32x4 acc[4][4];
#pragma unroll
        for (int m = 0; m < 4; ++m)
#pragma unroll
            for (int n = 0; n < 4; ++n)
                acc[m][n] = (f32x4){0.f, 0.f, 0.f, 0.f};

#pragma unroll
        for (int ks = 0; ks < 16; ++ks) {
            const int k0 = ks * 32;
            bf16x8 af[4], bfr[4];
#pragma unroll
            for (int m = 0; m < 4; ++m) {
                f32x4 lo = *reinterpret_cast<const f32x4*>(xrow[m] + k0);
                f32x4 hi = *reinterpret_cast<const f32x4*>(xrow[m] + k0 + 4);
#pragma unroll
                for (int e = 0; e < 4; ++e) {
                    af[m][e]     = (short)f2bf(lo[e]);
                    af[m][e + 4] = (short)f2bf(hi[e]);
                }
            }
#pragma unroll
            for (int n = 0; n < 4; ++n)
                bfr[n] = *reinterpret_cast<const bf16x8*>(wrow_off[n] + k0);
#pragma unroll
            for (int m = 0; m < 4; ++m)
#pragma unroll
                for (int n = 0; n < 4; ++n)
                    acc[m][n] = __builtin_amdgcn_mfma_f32_16x16x32_bf16(
                        af[m], bfr[n], acc[m][n], 0, 0, 0);
        }

        if (mode == 0) {
#pragma unroll
            for (int m = 0; m < 4; ++m)
#pragma unroll
                for (int j = 0; j < 4; ++j) {
                    const int grow = rowBase + wm * 64 + m * 16 + g * 4 + j;
#pragma unroll
                    for (int n = 0; n < 4; ++n) {
                        const int gcol = colBase + wn * 64 + n * 16 + fr;
                        const float val = fmaxf(acc[m][n][j] + bias[gcol], 0.f);
                        qb[(size_t)grow * E_DIM + gcol] = f2bf(val);
                    }
                }
        } else {
            ushort* __restrict__ dstbuf = (mode == 1) ? kT : vT;
            // scatter transposed into TS[feat][l]
#pragma unroll
            for (int m = 0; m < 4; ++m)
#pragma unroll
                for (int j = 0; j < 4; ++j) {
                    const int lr_ = wm * 64 + m * 16 + g * 4 + j;
#pragma unroll
                    for (int n = 0; n < 4; ++n) {
                        const int fcl = wn * 64 + n * 16 + fr;
                        float val = acc[m][n][j] + bias[colBase + fcl];
                        if (mode == 1) val = fmaxf(val, 0.f);
                        TS[fcl * 136 + lr_] = f2bf(val);
                    }
                }
            __syncthreads();
#pragma unroll
            for (int i = 0; i < 8; ++i) {
                const int c = i * 256 + tid;
                const int r = c >> 4;              // local feature 0..127
                const int cc = c & 15;             // 16B chunk along l
                const size_t dst = ((size_t)(b * E_DIM + colBase + r)) * L_SEQ + lloc + cc * 8;
                *reinterpret_cast<uint4*>(&dstbuf[dst]) =
                    *reinterpret_cast<const uint4*>(&TS[r * 136 + cc * 8]);
            }
            __syncthreads();   // TS reused by next mode
        }
    }
}

// ---------------- out GEMM, same barrier-free pattern: attnb(bf16) @ Wo^T + bo -------
__global__ __launch_bounds__(256) void out2_kernel(
    const ushort* __restrict__ A, const ushort* __restrict__ W,
    const float* __restrict__ bias, float* __restrict__ outF)
{
    const int tid = threadIdx.x;
    const int lane = tid & 63;
    const int wid = tid >> 6;
    const int wm = wid >> 1, wn = wid & 1;
    const int rowBase = blockIdx.x * 128;
    const int colBase = blockIdx.y * 128;
    const int fr = lane & 15;
    const int g = lane >> 4;

    const ushort* arow[4];
    const ushort* wrow[4];
#pragma unroll
    for (int m = 0; m < 4; ++m)
        arow[m] = &A[(size_t)(rowBase + wm * 64 + m * 16 + fr) * E_DIM + g * 8];
#pragma unroll
    for (int n = 0; n < 4; ++n)
        wrow[n] = &W[(size_t)(colBase + wn * 64 + n * 16 + fr) * E_DIM + g * 8];

    f32x4 acc[4][4];
#pragma unroll
    for (int m = 0; m < 4; ++m)
#pragma unroll
        for (int n = 0; n < 4; ++n)
            acc[m][n] = (f32x4){0.f, 0.f, 0.f, 0.f};

#pragma unroll
    for (int ks = 0; ks < 16; ++ks) {
        const int k0 = ks * 32;
        bf16x8 af[4], bfr[4];
#pragma unroll
        for (int m = 0; m < 4; ++m)
            af[m] = *reinterpret_cast<const bf16x8*>(arow[m] + k0);
#pragma unroll
        for (int n = 0; n < 4; ++n)
            bfr[n] = *reinterpret_cast<const bf16x8*>(wrow[n] + k0);
#pragma unroll
        for (int m = 0; m < 4; ++m)
#pragma unroll
            for (int n = 0; n < 4; ++n)
                acc[m][n] = __builtin_amdgcn_mfma_f32_16x16x32_bf16(
                    af[m], bfr[n], acc[m][n], 0, 0, 0);
    }

#pragma unroll
    for (int m = 0; m < 4; ++m)
#pragma unroll
        for (int j = 0; j < 4; ++j) {
            const int grow = rowBase + wm * 64 + m * 16 + g * 4 + j;
#pragma unroll
            for (int n = 0; n < 4; ++n) {
                const int gcol = colBase + wn * 64 + n * 16 + fr;
                outF[(size_t)grow * E_DIM + gcol] = acc[m][n][j] + bias[gcol];
            }
        }
}

// ---------------- kv via MFMA, fused cos/sin from tables, no LDS ----------------
__global__ __launch_bounds__(256) void kv_kernel(
    const ushort* __restrict__ kT, const ushort* __restrict__ vT,
    const float* __restrict__ sintab, const float* __restrict__ costab,
    float* __restrict__ kv_part, float* __restrict__ sum_part)
{
    const int chunk = blockIdx.x;   // 0..7
    const int bh = blockIdx.y;      // 0..31
    const int tid = threadIdx.x;
    const int lane = tid & 63;
    const int w = tid >> 6;
    const int fr = lane & 15;
    const int g = lane >> 4;

    const size_t tbase = (size_t)bh * 64 * L_SEQ;

    f32x4 acc[8], accS[8];
#pragma unroll
    for (int n = 0; n < 8; ++n) {
        acc[n] = (f32x4){0.f, 0.f, 0.f, 0.f};
        accS[n] = (f32x4){0.f, 0.f, 0.f, 0.f};
    }

    const int lchunk = chunk * (L_SEQ / 8);
    for (int l0 = lchunk; l0 < lchunk + (L_SEQ / 8); l0 += 32) {
        const int col = l0 + g * 8;
        bf16x8 vf = *reinterpret_cast<const bf16x8*>(&vT[tbase + (size_t)(w * 16 + fr) * L_SEQ + col]);
        bf16x8 kf[4];
#pragma unroll
        for (int n = 0; n < 4; ++n)
            kf[n] = *reinterpret_cast<const bf16x8*>(&kT[tbase + (size_t)(n * 16 + fr) * L_SEQ + col]);
        float4 c0 = *reinterpret_cast<const float4*>(&costab[col]);
        float4 c1 = *reinterpret_cast<const float4*>(&costab[col + 4]);
        float4 s0 = *reinterpret_cast<const float4*>(&sintab[col]);
        float4 s1 = *reinterpret_cast<const float4*>(&sintab[col + 4]);
        const float c8[8] = {c0.x, c0.y, c0.z, c0.w, c1.x, c1.y, c1.z, c1.w};
        const float s8[8] = {s0.x, s0.y, s0.z, s0.w, s1.x, s1.y, s1.z, s1.w};
        bf16x8 afc, afs, cw, sw;
#pragma unroll
        for (int e = 0; e < 8; ++e) {
            const float v = bf2f((ushort)vf[e]);
            afc[e] = (short)f2bf(v * c8[e]);
            afs[e] = (short)f2bf(v * s8[e]);
            cw[e]  = (short)f2bf(c8[e]);
            sw[e]  = (short)f2bf(s8[e]);
        }
#pragma unroll
        for (int n = 0; n < 4; ++n) {
            acc[n]      = __builtin_amdgcn_mfma_f32_16x16x32_bf16(afc, kf[n], acc[n], 0, 0, 0);
            acc[n + 4]  = __builtin_amdgcn_mfma_f32_16x16x32_bf16(afs, kf[n], acc[n + 4], 0, 0, 0);
            accS[n]     = __builtin_amdgcn_mfma_f32_16x16x32_bf16(cw,  kf[n], accS[n], 0, 0, 0);
            accS[n + 4] = __builtin_amdgcn_mfma_f32_16x16x32_bf16(sw,  kf[n], accS[n + 4], 0, 0, 0);
        }
    }

    const size_t pbase = ((size_t)(chunk * 32 + bh)) * 8192;
#pragma unroll
    for (int n = 0; n < 8; ++n)
#pragma unroll
        for (int j = 0; j < 4; ++j)
            kv_part[pbase + (size_t)(w * 16 + g * 4 + j) * 128 + n * 16 + fr] = acc[n][j];
    if (w == 0 && g == 0) {
        const size_t sbase = (size_t)(chunk * 32 + bh) * 128;
#pragma unroll
        for (int n = 0; n < 8; ++n)
            sum_part[sbase + n * 16 + fr] = accS[n][0];
    }
}

// ---------------- reduce partials; emit bf16 kvT_ext[bh][80][128] ----------------
#define KVT_ROWS 80
#define KVT_STRIDE (KVT_ROWS * 128)
__global__ __launch_bounds__(256) void kv_reduce_kernel(
    const float* __restrict__ kv_part, const float* __restrict__ sum_part,
    ushort* __restrict__ kvT)
{
    const int bh = blockIdx.x;
    const int tid = threadIdx.x;
    ushort* kvb = kvT + (size_t)bh * KVT_STRIDE;
    for (int idx = tid; idx < 8192; idx += 256) {
        float s = 0.f;
#pragma unroll
        for (int c = 0; c < 8; ++c)
            s += kv_part[((size_t)(c * 32 + bh)) * 8192 + idx];
        kvb[idx] = f2bf(s);
    }
    if (tid < 128) {
        float s = 0.f;
#pragma unroll
        for (int c = 0; c < 8; ++c)
            s += sum_part[(size_t)(c * 32 + bh) * 128 + tid];
        const ushort hi = f2bf(s);
        const float lo = s - bf2f(hi);
        kvb[64 * 128 + tid] = hi;
        kvb[65 * 128 + tid] = f2bf(lo);
    }
    for (int idx = tid; idx < 14 * 128; idx += 256)
        kvb[66 * 128 + idx] = 0;
}

// ---------------- attention via MFMA: A-fragments scaled by cos/sin on the fly -------
__global__ __launch_bounds__(256) void attn_kernel(
    const ushort* __restrict__ Qb, const ushort* __restrict__ kvT,
    const float* __restrict__ sintab, const float* __restrict__ costab,
    ushort* __restrict__ attn_out)
{
    const int bh = blockIdx.y;
    const int b = bh >> 3, h = bh & 7;
    const int tid = threadIdx.x;
    const int lane = tid & 63;
    const int w = tid >> 6;

    __shared__ ushort Bs[KVT_ROWS][136];

#pragma unroll
    for (int i = 0; i < 5; ++i) {
        const int c = i * 256 + tid;
        const int d = c >> 4, cc = c & 15;
        *reinterpret_cast<uint4*>(&Bs[d][cc * 8]) =
            *reinterpret_cast<const uint4*>(&kvT[(size_t)bh * KVT_STRIDE + (size_t)c * 8]);
    }
    __syncthreads();

    const int rowBase = blockIdx.x * 256 + w * 64;
    const int fr = lane & 15;
    const int g = lane >> 4;

    float cvm[4], svm[4];
#pragma unroll
    for (int m = 0; m < 4; ++m) {
        const int l = (rowBase + m * 16 + fr) & (L_SEQ - 1);
        cvm[m] = costab[l];
        svm[m] = sintab[l];
    }

    f32x4 acc[4][5];
#pragma unroll
    for (int m = 0; m < 4; ++m)
#pragma unroll
        for (int n = 0; n < 5; ++n)
            acc[m][n] = (f32x4){0.f, 0.f, 0.f, 0.f};

#pragma unroll
    for (int ks = 0; ks < 4; ++ks) {
        const int kk = (ks & 1) * 32 + g * 8;
        const int kcomb = ks * 32 + g * 8;

        bf16x8 af[4];
#pragma unroll
        for (int m = 0; m < 4; ++m) {
            const int r = rowBase + m * 16 + fr;
            bf16x8 qf = *reinterpret_cast<const bf16x8*>(
                &Qb[((size_t)(b * L_SEQ) + r) * E_DIM + h * DHEAD + kk]);
            const float sc = (ks < 2) ? cvm[m] : svm[m];
#pragma unroll
            for (int e = 0; e < 8; ++e)
                af[m][e] = (short)f2bf(bf2f((ushort)qf[e]) * sc);
        }

        bf16x8 bfr[5];
#pragma unroll
        for (int n = 0; n < 5; ++n)
            bfr[n] = *reinterpret_cast<const bf16x8*>(&Bs[n * 16 + fr][kcomb]);
#pragma unroll
        for (int m = 0; m < 4; ++m)
#pragma unroll
            for (int n = 0; n < 5; ++n)
                acc[m][n] = __builtin_amdgcn_mfma_f32_16x16x32_bf16(af[m], bfr[n], acc[m][n], 0, 0, 0);
    }

#pragma unroll
    for (int m = 0; m < 4; ++m) {
#pragma unroll
        for (int j = 0; j < 4; ++j) {
            const float den = __shfl(acc[m][4][j], g * 16 + 0) + __shfl(acc[m][4][j], g * 16 + 1);
            const float z = 1.f / fmaxf(den, 1e-6f);
            const int grow = rowBase + m * 16 + g * 4 + j;
            const size_t obase = ((size_t)(b * L_SEQ) + grow) * E_DIM + h * DHEAD;
#pragma unroll
            for (int n = 0; n < 4; ++n)
                attn_out[obase + n * 16 + fr] = f2bf(acc[m][n][j] * z);
        }
    }
}

// ---------------- launch ----------------
extern "C" void kernel_launch(void* const* d_in, const int* in_sizes, int n_in,
                              void* d_out, int out_size, void* d_ws, size_t ws_size,
                              hipStream_t stream) {
    const float* x  = (const float*)d_in[0];
    const float* Wq = (const float*)d_in[1];
    const float* bq = (const float*)d_in[2];
    const float* Wk = (const float*)d_in[3];
    const float* bk = (const float*)d_in[4];
    const float* Wv = (const float*)d_in[5];
    const float* bv = (const float*)d_in[6];
    const float* Wo = (const float*)d_in[7];
    const float* bo = (const float*)d_in[8];
    float* out = (float*)d_out;

    char* ws = (char*)d_ws;
    size_t off = 0;
    auto alloc = [&](size_t bytes) -> char* {
        char* p = ws + off;
        off += (bytes + 255) & ~(size_t)255;
        return p;
    };

    const size_t big = (size_t)NROWS * E_DIM * sizeof(ushort);   // 16.8 MB
    ushort* wqb = (ushort*)alloc(512 * 512 * sizeof(ushort));
    ushort* wkb = (ushort*)alloc(512 * 512 * sizeof(ushort));
    ushort* wvb = (ushort*)alloc(512 * 512 * sizeof(ushort));
    ushort* wob = (ushort*)alloc(512 * 512 * sizeof(ushort));
    ushort* qb  = (ushort*)alloc(big);   // relu(q), [l][e]
    ushort* kT  = (ushort*)alloc(big);   // relu(k) transposed [bh][k][l]
    ushort* vT  = (ushort*)alloc(big);   // v transposed [bh][d][l]
    float* kv_part  = (float*)alloc((size_t)8 * 32 * 8192 * sizeof(float));
    float* sum_part = (float*)alloc((size_t)8 * 32 * 128 * sizeof(float));
    ushort* kvT     = (ushort*)alloc((size_t)32 * KVT_STRIDE * sizeof(ushort));
    float* sintab   = (float*)alloc(L_SEQ * sizeof(float));
    float* costab   = (float*)alloc(L_SEQ * sizeof(float));
    ushort* attnb = kT;  // kT consumed by kv_kernel before attn_kernel writes

    convert_w_kernel<<<dim3(256, 5), 256, 0, stream>>>(
        Wq, Wk, Wv, Wo, wqb, wkb, wvb, wob, sintab, costab);

    qkv2_kernel<<<dim3(128, 4), 256, 0, stream>>>(
        x, wqb, wkb, wvb, bq, bk, bv, qb, kT, vT);

    kv_kernel<<<dim3(8, 32), 256, 0, stream>>>(kT, vT, sintab, costab, kv_part, sum_part);
    kv_reduce_kernel<<<32, 256, 0, stream>>>(kv_part, sum_part, kvT);

    attn_kernel<<<dim3(16, 32), 256, 0, stream>>>(qb, kvT, sintab, costab, attnb);

    out2_kernel<<<dim3(128, 4), 256, 0, stream>>>(attnb, wob, bo, out);
}

// Round 10
// 112.538 us; speedup vs baseline: 1.7074x; 1.7074x over previous
//
#include <hip/hip_runtime.h>
#include <hip/hip_bf16.h>

#define L_SEQ 4096
#define E_DIM 512
#define NHEAD 8
#define DHEAD 64
#define NBATCH 4
#define NROWS (NBATCH * L_SEQ)   // 16384

typedef short bf16x8 __attribute__((ext_vector_type(8)));
typedef float f32x4 __attribute__((ext_vector_type(4)));

__device__ __forceinline__ float bf2f(ushort u) {
    union { float f; unsigned int i; } x;
    x.i = ((unsigned int)u) << 16;
    return x.f;
}
__device__ __forceinline__ ushort f2bf(float f) {
    unsigned int u = __float_as_uint(f);
    unsigned int r = 0x7fffu + ((u >> 16) & 1u);
    u += r;
    return (ushort)(u >> 16);
}

#define GLD16(gptr, lptr) \
    __builtin_amdgcn_global_load_lds( \
        (const __attribute__((address_space(1))) void*)(gptr), \
        (__attribute__((address_space(3))) void*)(lptr), 16, 0, 0)

#define BAR_LGKM() do { \
    asm volatile("s_waitcnt lgkmcnt(0)" ::: "memory"); \
    __builtin_amdgcn_sched_barrier(0); \
    __builtin_amdgcn_s_barrier(); \
    __builtin_amdgcn_sched_barrier(0); } while (0)

// ---------------- fp32 -> bf16 conversion (x) ----------------
__global__ void convert_kernel(const float* __restrict__ in, ushort* __restrict__ out, int n4) {
    int stride = gridDim.x * blockDim.x;
    for (int i = blockIdx.x * blockDim.x + threadIdx.x; i < n4; i += stride) {
        float4 f = reinterpret_cast<const float4*>(in)[i];
        ushort4 o;
        o.x = f2bf(f.x); o.y = f2bf(f.y); o.z = f2bf(f.z); o.w = f2bf(f.w);
        reinterpret_cast<ushort4*>(out)[i] = o;
    }
}

// ---------------- weights conversion + sin/cos tables ----------------
__global__ __launch_bounds__(256) void convert_w_kernel(
    const float* __restrict__ w0, const float* __restrict__ w1,
    const float* __restrict__ w2, const float* __restrict__ w3,
    ushort* __restrict__ o0, ushort* __restrict__ o1,
    ushort* __restrict__ o2, ushort* __restrict__ o3,
    float* __restrict__ sintab, float* __restrict__ costab)
{
    const int tid = threadIdx.x;
    const int y = blockIdx.y;
    if (y == 4) {
        const int l = blockIdx.x * 256 + tid;
        if (blockIdx.x < 16) {
            const float ang = (float)(l + 1) * (1.5707963267948966f / (float)L_SEQ);
            sintab[l] = sinf(ang);
            costab[l] = cosf(ang);
        }
        return;
    }
    const float* in = (y == 0) ? w0 : (y == 1) ? w1 : (y == 2) ? w2 : w3;
    ushort* out = (y == 0) ? o0 : (y == 1) ? o1 : (y == 2) ? o2 : o3;
    const int i = blockIdx.x * 256 + tid;
    float4 f = reinterpret_cast<const float4*>(in)[i];
    ushort4 o;
    o.x = f2bf(f.x); o.y = f2bf(f.y); o.z = f2bf(f.z); o.w = f2bf(f.w);
    reinterpret_cast<ushort4*>(out)[i] = o;
}

// ---------------- persistent GEMM: 128x256 tile, BK=32, TRIPLE-buffered, 1 barrier/tile
// grid 256 x 512thr. Block p: rowBase=(p>>1)*128, colBase=(p&1)*256; NT modes.
// mode 0 (Q): relu -> qb bf16 [l][e];  mode 1 (K): relu -> kT[bh][k][l]
// mode 2 (V): -> vT[bh][d][l];         mode 3 (O): -> outF fp32 [l][e]
// LDS: 3 bufs x (A 8KB | B 16KB) = 72KB + TS 33KB = 105KB.
// Swizzle: slot s of row holds global chunk s ^ (row&3) ^ ((row>>2)&3)  (2-way, free).
// Tile: STAGE(gt+2)->buf[(gt+2)%3] issued FIRST (no hazard with buf[gt]) ->
//       8 ds_read -> lgkmcnt(0) -> 16 MFMA -> vmcnt(3) -> ONE s_barrier.
template<int MODE_BASE, int NT>
__global__ __launch_bounds__(512) void gemm4_kernel(
    const ushort* __restrict__ A,
    const ushort* __restrict__ wq, const ushort* __restrict__ wk,
    const ushort* __restrict__ wv, const ushort* __restrict__ wo,
    const float* __restrict__ bq, const float* __restrict__ bk,
    const float* __restrict__ bv, const float* __restrict__ bo,
    ushort* __restrict__ qb, ushort* __restrict__ kT, ushort* __restrict__ vT,
    float* __restrict__ outF)
{
    __shared__ ushort SH[36864 + 16896];   // 3x12288 bufs + TS[128][132]
    ushort* TS = SH + 36864;

    const int tid = threadIdx.x;
    const int lane = tid & 63;
    const int wid = tid >> 6;
    const int wm = wid >> 2;          // 0..1
    const int wn = wid & 3;           // 0..3
    const int p = blockIdx.x;
    const int rowBase = (p >> 1) * 128;
    const int colBase = (p & 1) * 256;
    const int fr = lane & 15;
    const int g = lane >> 4;
    constexpr int TOT = NT * 16;

    // staging maps
    const int a_row = tid >> 2, a_s = tid & 3;
    const int a_src = (a_s ^ (a_row & 3) ^ ((a_row >> 2) & 3)) * 8;
    const int b_row0 = tid >> 2, b_s0 = tid & 3;
    const int b_src0 = (b_s0 ^ (b_row0 & 3) ^ ((b_row0 >> 2) & 3)) * 8;
    const int b_row1 = (512 + tid) >> 2, b_s1 = tid & 3;
    const int b_src1 = (b_s1 ^ (b_row1 & 3) ^ ((b_row1 >> 2) & 3)) * 8;

    auto STAGE = [&](int gt2, int bufb) {
        const int mode = MODE_BASE + (gt2 >> 4);
        const ushort* __restrict__ W =
            (mode == 0) ? wq : (mode == 1) ? wk : (mode == 2) ? wv : wo;
        const int k0 = (gt2 & 15) * 32;
        GLD16(&A[(size_t)(rowBase + a_row) * E_DIM + k0 + a_src], &SH[bufb + tid * 8]);
        GLD16(&W[(size_t)(colBase + b_row0) * E_DIM + k0 + b_src0], &SH[bufb + 4096 + tid * 8]);
        GLD16(&W[(size_t)(colBase + b_row1) * E_DIM + k0 + b_src1], &SH[bufb + 4096 + (512 + tid) * 8]);
    };

    f32x4 acc[4][4];
#pragma unroll
    for (int m = 0; m < 4; ++m)
#pragma unroll
        for (int n = 0; n < 4; ++n)
            acc[m][n] = (f32x4){0.f, 0.f, 0.f, 0.f};

    STAGE(0, 0);
    STAGE(1, 12288);
    asm volatile("s_waitcnt vmcnt(3)" ::: "memory");
    __builtin_amdgcn_sched_barrier(0);
    __builtin_amdgcn_s_barrier();
    __builtin_amdgcn_sched_barrier(0);

    const int sRead = (g ^ (fr & 3) ^ ((fr >> 2) & 3)) * 8;
    const int aroff = (wm * 64 + fr) * 32 + sRead;         // + m*512
    const int broff = 4096 + (wn * 64 + fr) * 32 + sRead;  // + n*512
    const int b = rowBase >> 12;
    const int lloc = rowBase & (L_SEQ - 1);

    int cur = 0;
    for (int gt = 0; gt < TOT; ++gt) {
        const int bufb = cur * 12288;
        if (gt + 2 < TOT) {
            const int st = (cur == 0) ? 2 : cur - 1;    // (cur+2)%3
            STAGE(gt + 2, st * 12288);
        }
        bf16x8 af[4], bfv[4];
#pragma unroll
        for (int m = 0; m < 4; ++m)
            af[m] = *reinterpret_cast<const bf16x8*>(&SH[bufb + aroff + m * 512]);
#pragma unroll
        for (int n = 0; n < 4; ++n)
            bfv[n] = *reinterpret_cast<const bf16x8*>(&SH[bufb + broff + n * 512]);
        asm volatile("s_waitcnt lgkmcnt(0)" ::: "memory");
        __builtin_amdgcn_sched_barrier(0);

        __builtin_amdgcn_s_setprio(1);
#pragma unroll
        for (int m = 0; m < 4; ++m)
#pragma unroll
            for (int n = 0; n < 4; ++n)
                acc[m][n] = __builtin_amdgcn_mfma_f32_16x16x32_bf16(
                    af[m], bfv[n], acc[m][n], 0, 0, 0);
        __builtin_amdgcn_s_setprio(0);
        __builtin_amdgcn_sched_barrier(0);

        const bool epi = ((gt & 15) == 15);
        if (epi) {
            const int mode = MODE_BASE + (gt >> 4);
            const float* __restrict__ bias =
                (mode == 0) ? bq : (mode == 1) ? bk : (mode == 2) ? bv : bo;
            if (mode == 0) {
#pragma unroll
                for (int m = 0; m < 4; ++m)
#pragma unroll
                    for (int j = 0; j < 4; ++j) {
                        const int grow = rowBase + wm * 64 + m * 16 + g * 4 + j;
#pragma unroll
                        for (int n = 0; n < 4; ++n) {
                            const int gcol = colBase + wn * 64 + n * 16 + fr;
                            const float val = fmaxf(acc[m][n][j] + bias[gcol], 0.f);
                            qb[(size_t)grow * E_DIM + gcol] = f2bf(val);
                        }
                    }
            } else if (mode == 3) {
#pragma unroll
                for (int m = 0; m < 4; ++m)
#pragma unroll
                    for (int j = 0; j < 4; ++j) {
                        const int grow = rowBase + wm * 64 + m * 16 + g * 4 + j;
#pragma unroll
                        for (int n = 0; n < 4; ++n) {
                            const int gcol = colBase + wn * 64 + n * 16 + fr;
                            outF[(size_t)grow * E_DIM + gcol] = acc[m][n][j] + bias[gcol];
                        }
                    }
            } else {
                ushort* __restrict__ dstbuf = (mode == 1) ? kT : vT;
#pragma unroll
                for (int ph = 0; ph < 2; ++ph) {
                    BAR_LGKM();
                    if ((wn >> 1) == ph) {
#pragma unroll
                        for (int m = 0; m < 4; ++m)
#pragma unroll
                            for (int j = 0; j < 4; ++j) {
                                const int lr_ = wm * 64 + m * 16 + g * 4 + j;
#pragma unroll
                                for (int n = 0; n < 4; ++n) {
                                    const int fcl = (wn & 1) * 64 + n * 16 + fr;
                                    float val = acc[m][n][j] + bias[colBase + ph * 128 + fcl];
                                    if (mode == 1) val = fmaxf(val, 0.f);
                                    TS[fcl * 132 + lr_] = f2bf(val);
                                }
                            }
                    }
                    BAR_LGKM();
#pragma unroll
                    for (int i = 0; i < 4; ++i) {
                        const int c = i * 512 + tid;
                        const int r = c >> 4;
                        const int cc = c & 15;
                        const int gfeat = colBase + ph * 128 + r;
                        const size_t dst = ((size_t)(b * E_DIM + gfeat)) * L_SEQ + lloc + cc * 8;
                        *reinterpret_cast<uint4*>(&dstbuf[dst]) =
                            *reinterpret_cast<const uint4*>(&TS[r * 132 + cc * 8]);
                    }
                }
            }
#pragma unroll
            for (int m = 0; m < 4; ++m)
#pragma unroll
                for (int n = 0; n < 4; ++n)
                    acc[m][n] = (f32x4){0.f, 0.f, 0.f, 0.f};
        }

        if (gt < TOT - 1) {
            if (epi || gt + 2 >= TOT) asm volatile("s_waitcnt vmcnt(0)" ::: "memory");
            else                      asm volatile("s_waitcnt vmcnt(3)" ::: "memory");
            __builtin_amdgcn_sched_barrier(0);
            __builtin_amdgcn_s_barrier();
            __builtin_amdgcn_sched_barrier(0);
        }
        cur = (cur == 2) ? 0 : cur + 1;
    }
}

// ---------------- kv via MFMA, fused cos/sin from tables, no LDS ----------------
__global__ __launch_bounds__(256) void kv_kernel(
    const ushort* __restrict__ kT, const ushort* __restrict__ vT,
    const float* __restrict__ sintab, const float* __restrict__ costab,
    float* __restrict__ kv_part, float* __restrict__ sum_part)
{
    const int chunk = blockIdx.x;   // 0..7
    const int bh = blockIdx.y;      // 0..31
    const int tid = threadIdx.x;
    const int lane = tid & 63;
    const int w = tid >> 6;
    const int fr = lane & 15;
    const int g = lane >> 4;

    const size_t tbase = (size_t)bh * 64 * L_SEQ;

    f32x4 acc[8], accS[8];
#pragma unroll
    for (int n = 0; n < 8; ++n) {
        acc[n] = (f32x4){0.f, 0.f, 0.f, 0.f};
        accS[n] = (f32x4){0.f, 0.f, 0.f, 0.f};
    }

    const int lchunk = chunk * (L_SEQ / 8);
    for (int l0 = lchunk; l0 < lchunk + (L_SEQ / 8); l0 += 32) {
        const int col = l0 + g * 8;
        bf16x8 vf = *reinterpret_cast<const bf16x8*>(&vT[tbase + (size_t)(w * 16 + fr) * L_SEQ + col]);
        bf16x8 kf[4];
#pragma unroll
        for (int n = 0; n < 4; ++n)
            kf[n] = *reinterpret_cast<const bf16x8*>(&kT[tbase + (size_t)(n * 16 + fr) * L_SEQ + col]);
        float4 c0 = *reinterpret_cast<const float4*>(&costab[col]);
        float4 c1 = *reinterpret_cast<const float4*>(&costab[col + 4]);
        float4 s0 = *reinterpret_cast<const float4*>(&sintab[col]);
        float4 s1 = *reinterpret_cast<const float4*>(&sintab[col + 4]);
        const float c8[8] = {c0.x, c0.y, c0.z, c0.w, c1.x, c1.y, c1.z, c1.w};
        const float s8[8] = {s0.x, s0.y, s0.z, s0.w, s1.x, s1.y, s1.z, s1.w};
        bf16x8 afc, afs, cw, sw;
#pragma unroll
        for (int e = 0; e < 8; ++e) {
            const float v = bf2f((ushort)vf[e]);
            afc[e] = (short)f2bf(v * c8[e]);
            afs[e] = (short)f2bf(v * s8[e]);
            cw[e]  = (short)f2bf(c8[e]);
            sw[e]  = (short)f2bf(s8[e]);
        }
#pragma unroll
        for (int n = 0; n < 4; ++n) {
            acc[n]      = __builtin_amdgcn_mfma_f32_16x16x32_bf16(afc, kf[n], acc[n], 0, 0, 0);
            acc[n + 4]  = __builtin_amdgcn_mfma_f32_16x16x32_bf16(afs, kf[n], acc[n + 4], 0, 0, 0);
            accS[n]     = __builtin_amdgcn_mfma_f32_16x16x32_bf16(cw,  kf[n], accS[n], 0, 0, 0);
            accS[n + 4] = __builtin_amdgcn_mfma_f32_16x16x32_bf16(sw,  kf[n], accS[n + 4], 0, 0, 0);
        }
    }

    const size_t pbase = ((size_t)(chunk * 32 + bh)) * 8192;
#pragma unroll
    for (int n = 0; n < 8; ++n)
#pragma unroll
        for (int j = 0; j < 4; ++j)
            kv_part[pbase + (size_t)(w * 16 + g * 4 + j) * 128 + n * 16 + fr] = acc[n][j];
    if (w == 0 && g == 0) {
        const size_t sbase = (size_t)(chunk * 32 + bh) * 128;
#pragma unroll
        for (int n = 0; n < 8; ++n)
            sum_part[sbase + n * 16 + fr] = accS[n][0];
    }
}

// ---------------- reduce partials; emit bf16 kvT_ext[bh][80][128] ----------------
#define KVT_ROWS 80
#define KVT_STRIDE (KVT_ROWS * 128)
__global__ __launch_bounds__(256) void kv_reduce_kernel(
    const float* __restrict__ kv_part, const float* __restrict__ sum_part,
    ushort* __restrict__ kvT)
{
    const int bh = blockIdx.x;
    const int tid = threadIdx.x;
    ushort* kvb = kvT + (size_t)bh * KVT_STRIDE;
    for (int idx = tid; idx < 8192; idx += 256) {
        float s = 0.f;
#pragma unroll
        for (int c = 0; c < 8; ++c)
            s += kv_part[((size_t)(c * 32 + bh)) * 8192 + idx];
        kvb[idx] = f2bf(s);
    }
    if (tid < 128) {
        float s = 0.f;
#pragma unroll
        for (int c = 0; c < 8; ++c)
            s += sum_part[(size_t)(c * 32 + bh) * 128 + tid];
        const ushort hi = f2bf(s);
        const float lo = s - bf2f(hi);
        kvb[64 * 128 + tid] = hi;
        kvb[65 * 128 + tid] = f2bf(lo);
    }
    for (int idx = tid; idx < 14 * 128; idx += 256)
        kvb[66 * 128 + idx] = 0;
}

// ---------------- attention via MFMA: A-fragments scaled by cos/sin on the fly -------
__global__ __launch_bounds__(256) void attn_kernel(
    const ushort* __restrict__ Qb, const ushort* __restrict__ kvT,
    const float* __restrict__ sintab, const float* __restrict__ costab,
    ushort* __restrict__ attn_out)
{
    const int bh = blockIdx.y;
    const int b = bh >> 3, h = bh & 7;
    const int tid = threadIdx.x;
    const int lane = tid & 63;
    const int w = tid >> 6;

    __shared__ ushort Bs[KVT_ROWS][136];

#pragma unroll
    for (int i = 0; i < 5; ++i) {
        const int c = i * 256 + tid;
        const int d = c >> 4, cc = c & 15;
        *reinterpret_cast<uint4*>(&Bs[d][cc * 8]) =
            *reinterpret_cast<const uint4*>(&kvT[(size_t)bh * KVT_STRIDE + (size_t)c * 8]);
    }
    __syncthreads();

    const int rowBase = blockIdx.x * 256 + w * 64;
    const int fr = lane & 15;
    const int g = lane >> 4;

    float cvm[4], svm[4];
#pragma unroll
    for (int m = 0; m < 4; ++m) {
        const int l = (rowBase + m * 16 + fr) & (L_SEQ - 1);
        cvm[m] = costab[l];
        svm[m] = sintab[l];
    }

    f32x4 acc[4][5];
#pragma unroll
    for (int m = 0; m < 4; ++m)
#pragma unroll
        for (int n = 0; n < 5; ++n)
            acc[m][n] = (f32x4){0.f, 0.f, 0.f, 0.f};

#pragma unroll
    for (int ks = 0; ks < 4; ++ks) {
        const int kk = (ks & 1) * 32 + g * 8;
        const int kcomb = ks * 32 + g * 8;

        bf16x8 af[4];
#pragma unroll
        for (int m = 0; m < 4; ++m) {
            const int r = rowBase + m * 16 + fr;
            bf16x8 qf = *reinterpret_cast<const bf16x8*>(
                &Qb[((size_t)(b * L_SEQ) + r) * E_DIM + h * DHEAD + kk]);
            const float sc = (ks < 2) ? cvm[m] : svm[m];
#pragma unroll
            for (int e = 0; e < 8; ++e)
                af[m][e] = (short)f2bf(bf2f((ushort)qf[e]) * sc);
        }

        bf16x8 bfr[5];
#pragma unroll
        for (int n = 0; n < 5; ++n)
            bfr[n] = *reinterpret_cast<const bf16x8*>(&Bs[n * 16 + fr][kcomb]);
#pragma unroll
        for (int m = 0; m < 4; ++m)
#pragma unroll
            for (int n = 0; n < 5; ++n)
                acc[m][n] = __builtin_amdgcn_mfma_f32_16x16x32_bf16(af[m], bfr[n], acc[m][n], 0, 0, 0);
    }

#pragma unroll
    for (int m = 0; m < 4; ++m) {
#pragma unroll
        for (int j = 0; j < 4; ++j) {
            const float den = __shfl(acc[m][4][j], g * 16 + 0) + __shfl(acc[m][4][j], g * 16 + 1);
            const float z = 1.f / fmaxf(den, 1e-6f);
            const int grow = rowBase + m * 16 + g * 4 + j;
            const size_t obase = ((size_t)(b * L_SEQ) + grow) * E_DIM + h * DHEAD;
#pragma unroll
            for (int n = 0; n < 4; ++n)
                attn_out[obase + n * 16 + fr] = f2bf(acc[m][n][j] * z);
        }
    }
}

// ---------------- launch ----------------
extern "C" void kernel_launch(void* const* d_in, const int* in_sizes, int n_in,
                              void* d_out, int out_size, void* d_ws, size_t ws_size,
                              hipStream_t stream) {
    const float* x  = (const float*)d_in[0];
    const float* Wq = (const float*)d_in[1];
    const float* bq = (const float*)d_in[2];
    const float* Wk = (const float*)d_in[3];
    const float* bk = (const float*)d_in[4];
    const float* Wv = (const float*)d_in[5];
    const float* bv = (const float*)d_in[6];
    const float* Wo = (const float*)d_in[7];
    const float* bo = (const float*)d_in[8];
    float* out = (float*)d_out;

    char* ws = (char*)d_ws;
    size_t off = 0;
    auto alloc = [&](size_t bytes) -> char* {
        char* p = ws + off;
        off += (bytes + 255) & ~(size_t)255;
        return p;
    };

    const size_t big = (size_t)NROWS * E_DIM * sizeof(ushort);   // 16.8 MB
    ushort* xb  = (ushort*)alloc(big);
    ushort* wqb = (ushort*)alloc(512 * 512 * sizeof(ushort));
    ushort* wkb = (ushort*)alloc(512 * 512 * sizeof(ushort));
    ushort* wvb = (ushort*)alloc(512 * 512 * sizeof(ushort));
    ushort* wob = (ushort*)alloc(512 * 512 * sizeof(ushort));
    ushort* qb  = (ushort*)alloc(big);   // relu(q), [l][e]
    ushort* kT  = (ushort*)alloc(big);   // relu(k) transposed [bh][k][l]
    ushort* vT  = (ushort*)alloc(big);   // v transposed [bh][d][l]
    float* kv_part  = (float*)alloc((size_t)8 * 32 * 8192 * sizeof(float));
    float* sum_part = (float*)alloc((size_t)8 * 32 * 128 * sizeof(float));
    ushort* kvT     = (ushort*)alloc((size_t)32 * KVT_STRIDE * sizeof(ushort));
    float* sintab   = (float*)alloc(L_SEQ * sizeof(float));
    float* costab   = (float*)alloc(L_SEQ * sizeof(float));
    ushort* attnb = kT;  // kT consumed by kv_kernel before attn_kernel writes

    convert_kernel<<<2048, 256, 0, stream>>>(x, xb, NROWS * E_DIM / 4);
    convert_w_kernel<<<dim3(256, 5), 256, 0, stream>>>(
        Wq, Wk, Wv, Wo, wqb, wkb, wvb, wob, sintab, costab);

    // QKV: persistent, 256 blocks x 3 modes (48 K-tiles)
    gemm4_kernel<0, 3><<<256, 512, 0, stream>>>(
        xb, wqb, wkb, wvb, wob, bq, bk, bv, bo, qb, kT, vT, nullptr);

    kv_kernel<<<dim3(8, 32), 256, 0, stream>>>(kT, vT, sintab, costab, kv_part, sum_part);
    kv_reduce_kernel<<<32, 256, 0, stream>>>(kv_part, sum_part, kvT);

    attn_kernel<<<dim3(16, 32), 256, 0, stream>>>(qb, kvT, sintab, costab, attnb);

    // out GEMM: 256 blocks x 1 mode (16 K-tiles)
    gemm4_kernel<3, 1><<<256, 512, 0, stream>>>(
        attnb, wqb, wkb, wvb, wob, bq, bk, bv, bo, nullptr, nullptr, nullptr, out);
}

// Round 11
// 108.375 us; speedup vs baseline: 1.7730x; 1.0384x over previous
//
#include <hip/hip_runtime.h>
#include <hip/hip_bf16.h>

#define L_SEQ 4096
#define E_DIM 512
#define NHEAD 8
#define DHEAD 64
#define NBATCH 4
#define NROWS (NBATCH * L_SEQ)   // 16384

typedef short bf16x8 __attribute__((ext_vector_type(8)));
typedef float f32x4 __attribute__((ext_vector_type(4)));

__device__ __forceinline__ float bf2f(ushort u) {
    union { float f; unsigned int i; } x;
    x.i = ((unsigned int)u) << 16;
    return x.f;
}
__device__ __forceinline__ ushort f2bf(float f) {
    unsigned int u = __float_as_uint(f);
    unsigned int r = 0x7fffu + ((u >> 16) & 1u);
    u += r;
    return (ushort)(u >> 16);
}

#define GLD16(gptr, lptr) \
    __builtin_amdgcn_global_load_lds( \
        (const __attribute__((address_space(1))) void*)(gptr), \
        (__attribute__((address_space(3))) void*)(lptr), 16, 0, 0)

#define BAR_LGKM() do { \
    asm volatile("s_waitcnt lgkmcnt(0)" ::: "memory"); \
    __builtin_amdgcn_sched_barrier(0); \
    __builtin_amdgcn_s_barrier(); \
    __builtin_amdgcn_sched_barrier(0); } while (0)

// ---------------- fp32 -> bf16 conversion (x) ----------------
__global__ void convert_kernel(const float* __restrict__ in, ushort* __restrict__ out, int n4) {
    int stride = gridDim.x * blockDim.x;
    for (int i = blockIdx.x * blockDim.x + threadIdx.x; i < n4; i += stride) {
        float4 f = reinterpret_cast<const float4*>(in)[i];
        ushort4 o;
        o.x = f2bf(f.x); o.y = f2bf(f.y); o.z = f2bf(f.z); o.w = f2bf(f.w);
        reinterpret_cast<ushort4*>(out)[i] = o;
    }
}

// ---------------- weights conversion + sin/cos tables ----------------
__global__ __launch_bounds__(256) void convert_w_kernel(
    const float* __restrict__ w0, const float* __restrict__ w1,
    const float* __restrict__ w2, const float* __restrict__ w3,
    ushort* __restrict__ o0, ushort* __restrict__ o1,
    ushort* __restrict__ o2, ushort* __restrict__ o3,
    float* __restrict__ sintab, float* __restrict__ costab)
{
    const int tid = threadIdx.x;
    const int y = blockIdx.y;
    if (y == 4) {
        const int l = blockIdx.x * 256 + tid;
        if (blockIdx.x < 16) {
            const float ang = (float)(l + 1) * (1.5707963267948966f / (float)L_SEQ);
            sintab[l] = sinf(ang);
            costab[l] = cosf(ang);
        }
        return;
    }
    const float* in = (y == 0) ? w0 : (y == 1) ? w1 : (y == 2) ? w2 : w3;
    ushort* out = (y == 0) ? o0 : (y == 1) ? o1 : (y == 2) ? o2 : o3;
    const int i = blockIdx.x * 256 + tid;
    float4 f = reinterpret_cast<const float4*>(in)[i];
    ushort4 o;
    o.x = f2bf(f.x); o.y = f2bf(f.y); o.z = f2bf(f.z); o.w = f2bf(f.w);
    reinterpret_cast<ushort4*>(out)[i] = o;
}

// ---------------- pipelined GEMM: 128x256 tile, BK=64, dbuf, counted vmcnt ---------
// QKV variant: linear grid 768; job = p % 6 (mode = job>>1, colBase = (job&1)*256),
//   rowBase = (p / 6) * 128. Job-fastest ordering: consecutive blocks = same row
//   panel -> x fetched once, L2/L3-shared across its 6 jobs.
// OUT variant (MODE_BASE==3): grid 256; rowBase=(p>>1)*128, colBase=(p&1)*256.
// mode 0 (Q): relu -> qb bf16 [l][e];  mode 1 (K): relu -> kT[bh][k][l]
// mode 2 (V): -> vT[bh][d][l];         mode 3 (O): -> outF fp32 [l][e]
// LDS: 2 x (A 16KB | B 32KB) = 96KB + TS[128][132] 33KB.
template<int MODE_BASE>
__global__ __launch_bounds__(512) void gemm5_kernel(
    const ushort* __restrict__ A,
    const ushort* __restrict__ wq, const ushort* __restrict__ wk,
    const ushort* __restrict__ wv, const ushort* __restrict__ wo,
    const float* __restrict__ bq, const float* __restrict__ bk,
    const float* __restrict__ bv, const float* __restrict__ bo,
    ushort* __restrict__ qb, ushort* __restrict__ kT, ushort* __restrict__ vT,
    float* __restrict__ outF)
{
    __shared__ ushort SH[66048];        // 96KB bufs + 33KB TS
    ushort* TS = SH + 49152;

    const int tid = threadIdx.x;
    const int lane = tid & 63;
    const int wid = tid >> 6;
    const int wm = wid >> 2;
    const int wn = wid & 3;
    const int p = blockIdx.x;

    int mode, rowBase, colBase;
    if (MODE_BASE == 3) {
        mode = 3;
        rowBase = (p >> 1) * 128;
        colBase = (p & 1) * 256;
    } else {
        const int panel = p / 6;
        const int job = p - panel * 6;
        mode = job >> 1;
        colBase = (job & 1) * 256;
        rowBase = panel * 128;
    }

    const ushort* __restrict__ W =
        (mode == 0) ? wq : (mode == 1) ? wk : (mode == 2) ? wv : wo;
    const float* __restrict__ bias =
        (mode == 0) ? bq : (mode == 1) ? bk : (mode == 2) ? bv : bo;

    const int fr = lane & 15;
    const int g = lane >> 4;
    const int fr7 = fr & 7;
    const int sc_row = tid >> 3;
    const int sc_ch  = tid & 7;

    f32x4 acc[4][4];
#pragma unroll
    for (int m = 0; m < 4; ++m)
#pragma unroll
        for (int n = 0; n < 4; ++n)
            acc[m][n] = (f32x4){0.f, 0.f, 0.f, 0.f};

    auto STAGE = [&](int kt) {
        const int k0 = kt * 64;
        const int bufb = (kt & 1) * 24576;
#pragma unroll
        for (int i = 0; i < 2; ++i) {
            const int row = i * 64 + sc_row;
            const int srcc = (sc_ch ^ (row & 7)) * 8;
            GLD16(&A[(size_t)(rowBase + row) * E_DIM + k0 + srcc],
                  &SH[bufb + (i * 512 + tid) * 8]);
        }
#pragma unroll
        for (int i = 0; i < 4; ++i) {
            const int row = i * 64 + sc_row;
            const int srcc = (sc_ch ^ (row & 7)) * 8;
            GLD16(&W[(size_t)(colBase + row) * E_DIM + k0 + srcc],
                  &SH[bufb + 8192 + (i * 512 + tid) * 8]);
        }
    };

    STAGE(0);
    STAGE(1);
    asm volatile("s_waitcnt vmcnt(6)" ::: "memory");
    __builtin_amdgcn_sched_barrier(0);
    __builtin_amdgcn_s_barrier();
    __builtin_amdgcn_sched_barrier(0);

    const int kch0 = (g ^ fr7) * 8;
    const int kch1 = ((4 + g) ^ fr7) * 8;
    const int aroff = (wm * 64 + fr) * 64;
    const int broff = 8192 + (wn * 64 + fr) * 64;
    const int b = rowBase >> 12;
    const int lloc = rowBase & (L_SEQ - 1);

    for (int gt = 0; gt < 8; ++gt) {
        const int base = (gt & 1) * 24576;
        bf16x8 af[2][4], bfv[2][4];
#pragma unroll
        for (int m = 0; m < 4; ++m) {
            af[0][m] = *reinterpret_cast<const bf16x8*>(&SH[base + aroff + m * 1024 + kch0]);
            af[1][m] = *reinterpret_cast<const bf16x8*>(&SH[base + aroff + m * 1024 + kch1]);
        }
#pragma unroll
        for (int n = 0; n < 4; ++n) {
            bfv[0][n] = *reinterpret_cast<const bf16x8*>(&SH[base + broff + n * 1024 + kch0]);
            bfv[1][n] = *reinterpret_cast<const bf16x8*>(&SH[base + broff + n * 1024 + kch1]);
        }
        BAR_LGKM();

        if (gt + 2 < 8) STAGE(gt + 2);

        __builtin_amdgcn_s_setprio(1);
#pragma unroll
        for (int kk = 0; kk < 2; ++kk)
#pragma unroll
            for (int m = 0; m < 4; ++m)
#pragma unroll
                for (int n = 0; n < 4; ++n)
                    acc[m][n] = __builtin_amdgcn_mfma_f32_16x16x32_bf16(
                        af[kk][m], bfv[kk][n], acc[m][n], 0, 0, 0);
        __builtin_amdgcn_s_setprio(0);
        __builtin_amdgcn_sched_barrier(0);

        if (gt < 7) {
            if (gt + 2 < 8) asm volatile("s_waitcnt vmcnt(6)" ::: "memory");
            else            asm volatile("s_waitcnt vmcnt(0)" ::: "memory");
            __builtin_amdgcn_sched_barrier(0);
            __builtin_amdgcn_s_barrier();
            __builtin_amdgcn_sched_barrier(0);
        }
    }

    // ---------------- epilogues ----------------
    if (mode == 0) {
        // (sin/cos applied downstream; write relu(q) only)
        const float* __restrict__ bq_ = bias;
#pragma unroll
        for (int m = 0; m < 4; ++m)
#pragma unroll
            for (int j = 0; j < 4; ++j) {
                const int grow = rowBase + wm * 64 + m * 16 + g * 4 + j;
#pragma unroll
                for (int n = 0; n < 4; ++n) {
                    const int gcol = colBase + wn * 64 + n * 16 + fr;
                    const float val = fmaxf(acc[m][n][j] + bq_[gcol], 0.f);
                    qb[(size_t)grow * E_DIM + gcol] = f2bf(val);
                }
            }
    } else if (mode == 3) {
#pragma unroll
        for (int m = 0; m < 4; ++m)
#pragma unroll
            for (int j = 0; j < 4; ++j) {
                const int grow = rowBase + wm * 64 + m * 16 + g * 4 + j;
#pragma unroll
                for (int n = 0; n < 4; ++n) {
                    const int gcol = colBase + wn * 64 + n * 16 + fr;
                    outF[(size_t)grow * E_DIM + gcol] = acc[m][n][j] + bias[gcol];
                }
            }
    } else {
        ushort* __restrict__ dstbuf = (mode == 1) ? kT : vT;
#pragma unroll
        for (int ph = 0; ph < 2; ++ph) {
            BAR_LGKM();
            if ((wn >> 1) == ph) {
#pragma unroll
                for (int m = 0; m < 4; ++m)
#pragma unroll
                    for (int j = 0; j < 4; ++j) {
                        const int lr_ = wm * 64 + m * 16 + g * 4 + j;
#pragma unroll
                        for (int n = 0; n < 4; ++n) {
                            const int fcl = (wn & 1) * 64 + n * 16 + fr;
                            float val = acc[m][n][j] + bias[colBase + ph * 128 + fcl];
                            if (mode == 1) val = fmaxf(val, 0.f);
                            TS[fcl * 132 + lr_] = f2bf(val);
                        }
                    }
            }
            BAR_LGKM();
#pragma unroll
            for (int i = 0; i < 4; ++i) {
                const int c = i * 512 + tid;
                const int r = c >> 4;
                const int cc = c & 15;
                const int gfeat = colBase + ph * 128 + r;
                const size_t dst = ((size_t)(b * E_DIM + gfeat)) * L_SEQ + lloc + cc * 8;
                *reinterpret_cast<uint4*>(&dstbuf[dst]) =
                    *reinterpret_cast<const uint4*>(&TS[r * 132 + cc * 8]);
            }
        }
    }
}

// ---------------- kv via MFMA, fused cos/sin from tables, no LDS ----------------
__global__ __launch_bounds__(256) void kv_kernel(
    const ushort* __restrict__ kT, const ushort* __restrict__ vT,
    const float* __restrict__ sintab, const float* __restrict__ costab,
    float* __restrict__ kv_part, float* __restrict__ sum_part)
{
    const int chunk = blockIdx.x;   // 0..7
    const int bh = blockIdx.y;      // 0..31
    const int tid = threadIdx.x;
    const int lane = tid & 63;
    const int w = tid >> 6;
    const int fr = lane & 15;
    const int g = lane >> 4;

    const size_t tbase = (size_t)bh * 64 * L_SEQ;

    f32x4 acc[8], accS[8];
#pragma unroll
    for (int n = 0; n < 8; ++n) {
        acc[n] = (f32x4){0.f, 0.f, 0.f, 0.f};
        accS[n] = (f32x4){0.f, 0.f, 0.f, 0.f};
    }

    const int lchunk = chunk * (L_SEQ / 8);
    for (int l0 = lchunk; l0 < lchunk + (L_SEQ / 8); l0 += 32) {
        const int col = l0 + g * 8;
        bf16x8 vf = *reinterpret_cast<const bf16x8*>(&vT[tbase + (size_t)(w * 16 + fr) * L_SEQ + col]);
        bf16x8 kf[4];
#pragma unroll
        for (int n = 0; n < 4; ++n)
            kf[n] = *reinterpret_cast<const bf16x8*>(&kT[tbase + (size_t)(n * 16 + fr) * L_SEQ + col]);
        float4 c0 = *reinterpret_cast<const float4*>(&costab[col]);
        float4 c1 = *reinterpret_cast<const float4*>(&costab[col + 4]);
        float4 s0 = *reinterpret_cast<const float4*>(&sintab[col]);
        float4 s1 = *reinterpret_cast<const float4*>(&sintab[col + 4]);
        const float c8[8] = {c0.x, c0.y, c0.z, c0.w, c1.x, c1.y, c1.z, c1.w};
        const float s8[8] = {s0.x, s0.y, s0.z, s0.w, s1.x, s1.y, s1.z, s1.w};
        bf16x8 afc, afs, cw, sw;
#pragma unroll
        for (int e = 0; e < 8; ++e) {
            const float v = bf2f((ushort)vf[e]);
            afc[e] = (short)f2bf(v * c8[e]);
            afs[e] = (short)f2bf(v * s8[e]);
            cw[e]  = (short)f2bf(c8[e]);
            sw[e]  = (short)f2bf(s8[e]);
        }
#pragma unroll
        for (int n = 0; n < 4; ++n) {
            acc[n]      = __builtin_amdgcn_mfma_f32_16x16x32_bf16(afc, kf[n], acc[n], 0, 0, 0);
            acc[n + 4]  = __builtin_amdgcn_mfma_f32_16x16x32_bf16(afs, kf[n], acc[n + 4], 0, 0, 0);
            accS[n]     = __builtin_amdgcn_mfma_f32_16x16x32_bf16(cw,  kf[n], accS[n], 0, 0, 0);
            accS[n + 4] = __builtin_amdgcn_mfma_f32_16x16x32_bf16(sw,  kf[n], accS[n + 4], 0, 0, 0);
        }
    }

    const size_t pbase = ((size_t)(chunk * 32 + bh)) * 8192;
#pragma unroll
    for (int n = 0; n < 8; ++n)
#pragma unroll
        for (int j = 0; j < 4; ++j)
            kv_part[pbase + (size_t)(w * 16 + g * 4 + j) * 128 + n * 16 + fr] = acc[n][j];
    if (w == 0 && g == 0) {
        const size_t sbase = (size_t)(chunk * 32 + bh) * 128;
#pragma unroll
        for (int n = 0; n < 8; ++n)
            sum_part[sbase + n * 16 + fr] = accS[n][0];
    }
}

// ---------------- reduce partials; emit bf16 kvT_ext[bh][80][128] ----------------
#define KVT_ROWS 80
#define KVT_STRIDE (KVT_ROWS * 128)
__global__ __launch_bounds__(256) void kv_reduce_kernel(
    const float* __restrict__ kv_part, const float* __restrict__ sum_part,
    ushort* __restrict__ kvT)
{
    const int bh = blockIdx.x;
    const int tid = threadIdx.x;
    ushort* kvb = kvT + (size_t)bh * KVT_STRIDE;
    for (int idx = tid; idx < 8192; idx += 256) {
        float s = 0.f;
#pragma unroll
        for (int c = 0; c < 8; ++c)
            s += kv_part[((size_t)(c * 32 + bh)) * 8192 + idx];
        kvb[idx] = f2bf(s);
    }
    if (tid < 128) {
        float s = 0.f;
#pragma unroll
        for (int c = 0; c < 8; ++c)
            s += sum_part[(size_t)(c * 32 + bh) * 128 + tid];
        const ushort hi = f2bf(s);
        const float lo = s - bf2f(hi);
        kvb[64 * 128 + tid] = hi;
        kvb[65 * 128 + tid] = f2bf(lo);
    }
    for (int idx = tid; idx < 14 * 128; idx += 256)
        kvb[66 * 128 + idx] = 0;
}

// ---------------- attention via MFMA: A-fragments scaled by cos/sin on the fly -------
__global__ __launch_bounds__(256) void attn_kernel(
    const ushort* __restrict__ Qb, const ushort* __restrict__ kvT,
    const float* __restrict__ sintab, const float* __restrict__ costab,
    ushort* __restrict__ attn_out)
{
    const int bh = blockIdx.y;
    const int b = bh >> 3, h = bh & 7;
    const int tid = threadIdx.x;
    const int lane = tid & 63;
    const int w = tid >> 6;

    __shared__ ushort Bs[KVT_ROWS][136];

#pragma unroll
    for (int i = 0; i < 5; ++i) {
        const int c = i * 256 + tid;
        const int d = c >> 4, cc = c & 15;
        *reinterpret_cast<uint4*>(&Bs[d][cc * 8]) =
            *reinterpret_cast<const uint4*>(&kvT[(size_t)bh * KVT_STRIDE + (size_t)c * 8]);
    }
    __syncthreads();

    const int rowBase = blockIdx.x * 256 + w * 64;
    const int fr = lane & 15;
    const int g = lane >> 4;

    float cvm[4], svm[4];
#pragma unroll
    for (int m = 0; m < 4; ++m) {
        const int l = (rowBase + m * 16 + fr) & (L_SEQ - 1);
        cvm[m] = costab[l];
        svm[m] = sintab[l];
    }

    f32x4 acc[4][5];
#pragma unroll
    for (int m = 0; m < 4; ++m)
#pragma unroll
        for (int n = 0; n < 5; ++n)
            acc[m][n] = (f32x4){0.f, 0.f, 0.f, 0.f};

#pragma unroll
    for (int ks = 0; ks < 4; ++ks) {
        const int kk = (ks & 1) * 32 + g * 8;
        const int kcomb = ks * 32 + g * 8;

        bf16x8 af[4];
#pragma unroll
        for (int m = 0; m < 4; ++m) {
            const int r = rowBase + m * 16 + fr;
            bf16x8 qf = *reinterpret_cast<const bf16x8*>(
                &Qb[((size_t)(b * L_SEQ) + r) * E_DIM + h * DHEAD + kk]);
            const float sc = (ks < 2) ? cvm[m] : svm[m];
#pragma unroll
            for (int e = 0; e < 8; ++e)
                af[m][e] = (short)f2bf(bf2f((ushort)qf[e]) * sc);
        }

        bf16x8 bfr[5];
#pragma unroll
        for (int n = 0; n < 5; ++n)
            bfr[n] = *reinterpret_cast<const bf16x8*>(&Bs[n * 16 + fr][kcomb]);
#pragma unroll
        for (int m = 0; m < 4; ++m)
#pragma unroll
            for (int n = 0; n < 5; ++n)
                acc[m][n] = __builtin_amdgcn_mfma_f32_16x16x32_bf16(af[m], bfr[n], acc[m][n], 0, 0, 0);
    }

#pragma unroll
    for (int m = 0; m < 4; ++m) {
#pragma unroll
        for (int j = 0; j < 4; ++j) {
            const float den = __shfl(acc[m][4][j], g * 16 + 0) + __shfl(acc[m][4][j], g * 16 + 1);
            const float z = 1.f / fmaxf(den, 1e-6f);
            const int grow = rowBase + m * 16 + g * 4 + j;
            const size_t obase = ((size_t)(b * L_SEQ) + grow) * E_DIM + h * DHEAD;
#pragma unroll
            for (int n = 0; n < 4; ++n)
                attn_out[obase + n * 16 + fr] = f2bf(acc[m][n][j] * z);
        }
    }
}

// ---------------- launch ----------------
extern "C" void kernel_launch(void* const* d_in, const int* in_sizes, int n_in,
                              void* d_out, int out_size, void* d_ws, size_t ws_size,
                              hipStream_t stream) {
    const float* x  = (const float*)d_in[0];
    const float* Wq = (const float*)d_in[1];
    const float* bq = (const float*)d_in[2];
    const float* Wk = (const float*)d_in[3];
    const float* bk = (const float*)d_in[4];
    const float* Wv = (const float*)d_in[5];
    const float* bv = (const float*)d_in[6];
    const float* Wo = (const float*)d_in[7];
    const float* bo = (const float*)d_in[8];
    float* out = (float*)d_out;

    char* ws = (char*)d_ws;
    size_t off = 0;
    auto alloc = [&](size_t bytes) -> char* {
        char* p = ws + off;
        off += (bytes + 255) & ~(size_t)255;
        return p;
    };

    const size_t big = (size_t)NROWS * E_DIM * sizeof(ushort);   // 16.8 MB
    ushort* xb  = (ushort*)alloc(big);
    ushort* wqb = (ushort*)alloc(512 * 512 * sizeof(ushort));
    ushort* wkb = (ushort*)alloc(512 * 512 * sizeof(ushort));
    ushort* wvb = (ushort*)alloc(512 * 512 * sizeof(ushort));
    ushort* wob = (ushort*)alloc(512 * 512 * sizeof(ushort));
    ushort* qb  = (ushort*)alloc(big);   // relu(q), [l][e]
    ushort* kT  = (ushort*)alloc(big);   // relu(k) transposed [bh][k][l]
    ushort* vT  = (ushort*)alloc(big);   // v transposed [bh][d][l]
    float* kv_part  = (float*)alloc((size_t)8 * 32 * 8192 * sizeof(float));
    float* sum_part = (float*)alloc((size_t)8 * 32 * 128 * sizeof(float));
    ushort* kvT     = (ushort*)alloc((size_t)32 * KVT_STRIDE * sizeof(ushort));
    float* sintab   = (float*)alloc(L_SEQ * sizeof(float));
    float* costab   = (float*)alloc(L_SEQ * sizeof(float));
    ushort* attnb = kT;  // kT consumed by kv_kernel before attn_kernel writes

    convert_kernel<<<2048, 256, 0, stream>>>(x, xb, NROWS * E_DIM / 4);
    convert_w_kernel<<<dim3(256, 5), 256, 0, stream>>>(
        Wq, Wk, Wv, Wo, wqb, wkb, wvb, wob, sintab, costab);

    // QKV: 768 blocks, job-fastest ordering (job = id % 6, panel = id / 6)
    gemm5_kernel<0><<<768, 512, 0, stream>>>(
        xb, wqb, wkb, wvb, wob, bq, bk, bv, bo, qb, kT, vT, nullptr);

    kv_kernel<<<dim3(8, 32), 256, 0, stream>>>(kT, vT, sintab, costab, kv_part, sum_part);
    kv_reduce_kernel<<<32, 256, 0, stream>>>(kv_part, sum_part, kvT);

    attn_kernel<<<dim3(16, 32), 256, 0, stream>>>(qb, kvT, sintab, costab, attnb);

    // out GEMM: 256 blocks
    gemm5_kernel<3><<<256, 512, 0, stream>>>(
        attnb, wqb, wkb, wvb, wob, bq, bk, bv, bo, nullptr, nullptr, nullptr, out);
}

// Round 12
// 97.397 us; speedup vs baseline: 1.9729x; 1.1127x over previous
//
#include <hip/hip_runtime.h>
#include <hip/hip_bf16.h>

#define L_SEQ 4096
#define E_DIM 512
#define NHEAD 8
#define DHEAD 64
#define NBATCH 4
#define NROWS (NBATCH * L_SEQ)   // 16384

typedef short bf16x8 __attribute__((ext_vector_type(8)));
typedef float f32x4 __attribute__((ext_vector_type(4)));

__device__ __forceinline__ float bf2f(ushort u) {
    union { float f; unsigned int i; } x;
    x.i = ((unsigned int)u) << 16;
    return x.f;
}
__device__ __forceinline__ ushort f2bf(float f) {
    unsigned int u = __float_as_uint(f);
    unsigned int r = 0x7fffu + ((u >> 16) & 1u);
    u += r;
    return (ushort)(u >> 16);
}

#define GLD16(gptr, lptr) \
    __builtin_amdgcn_global_load_lds( \
        (const __attribute__((address_space(1))) void*)(gptr), \
        (__attribute__((address_space(3))) void*)(lptr), 16, 0, 0)

#define BAR_LGKM() do { \
    asm volatile("s_waitcnt lgkmcnt(0)" ::: "memory"); \
    __builtin_amdgcn_sched_barrier(0); \
    __builtin_amdgcn_s_barrier(); \
    __builtin_amdgcn_sched_barrier(0); } while (0)

// ---------------- fp32 -> bf16 conversion (x) ----------------
__global__ void convert_kernel(const float* __restrict__ in, ushort* __restrict__ out, int n4) {
    int stride = gridDim.x * blockDim.x;
    for (int i = blockIdx.x * blockDim.x + threadIdx.x; i < n4; i += stride) {
        float4 f = reinterpret_cast<const float4*>(in)[i];
        ushort4 o;
        o.x = f2bf(f.x); o.y = f2bf(f.y); o.z = f2bf(f.z); o.w = f2bf(f.w);
        reinterpret_cast<ushort4*>(out)[i] = o;
    }
}

// ---------------- weights conversion + sin/cos tables ----------------
__global__ __launch_bounds__(256) void convert_w_kernel(
    const float* __restrict__ w0, const float* __restrict__ w1,
    const float* __restrict__ w2, const float* __restrict__ w3,
    ushort* __restrict__ o0, ushort* __restrict__ o1,
    ushort* __restrict__ o2, ushort* __restrict__ o3,
    float* __restrict__ sintab, float* __restrict__ costab)
{
    const int tid = threadIdx.x;
    const int y = blockIdx.y;
    if (y == 4) {
        const int l = blockIdx.x * 256 + tid;
        if (blockIdx.x < 16) {
            const float ang = (float)(l + 1) * (1.5707963267948966f / (float)L_SEQ);
            sintab[l] = sinf(ang);
            costab[l] = cosf(ang);
        }
        return;
    }
    const float* in = (y == 0) ? w0 : (y == 1) ? w1 : (y == 2) ? w2 : w3;
    ushort* out = (y == 0) ? o0 : (y == 1) ? o1 : (y == 2) ? o2 : o3;
    const int i = blockIdx.x * 256 + tid;
    float4 f = reinterpret_cast<const float4*>(in)[i];
    ushort4 o;
    o.x = f2bf(f.x); o.y = f2bf(f.y); o.z = f2bf(f.z); o.w = f2bf(f.w);
    reinterpret_cast<ushort4*>(out)[i] = o;
}

// ---------------- pipelined GEMM: 128x128 tile, BK=64, dbuf, 2 blocks/CU ----------
// 256 threads (2x2 waves, wave-tile 64x64). LDS = 2 x (A 16KB | B 16KB) = 64KB ->
// TWO independent blocks per CU: one block's MFMA covers the other's barrier/drain.
// QKV variant (MODE_BASE 0): grid (128, 12); panel = blockIdx.x (mode-major -> a
//   panel's jobs share an XCD L2); mode = y>>2, colBase = (y&3)*128.
// OUT variant (MODE_BASE 3): grid (128, 4); colBase = y*128.
// mode 0 (Q): relu -> qb bf16 [l][e];  mode 1 (K): relu -> kT[bh][k][l]
// mode 2 (V): -> vT[bh][d][l];         mode 3 (O): -> outF fp32 [l][e]
// Swizzle (r6-verified): slot c16 holds source chunk c16^(row&7); read (kk*4+g)^(fr&7).
// Schedule (r7-verified): reads -> lgkm0+barA -> STAGE(t+2) -> MFMA -> vmcnt(8)+barB.
template<int MODE_BASE>
__global__ __launch_bounds__(256, 2) void gemm6_kernel(
    const ushort* __restrict__ A,
    const ushort* __restrict__ wq, const ushort* __restrict__ wk,
    const ushort* __restrict__ wv, const ushort* __restrict__ wo,
    const float* __restrict__ bq, const float* __restrict__ bk,
    const float* __restrict__ bv, const float* __restrict__ bo,
    ushort* __restrict__ qb, ushort* __restrict__ kT, ushort* __restrict__ vT,
    float* __restrict__ outF)
{
    __shared__ ushort SH[32768];        // 64KB: buf0 A|B, buf1 A|B; TS overlay after loop
    ushort* TS = SH;                    // TS[128][136] = 34.8KB, buffers dead by then

    const int tid = threadIdx.x;
    const int lane = tid & 63;
    const int wid = tid >> 6;
    const int wm = wid >> 1;            // 0..1
    const int wn = wid & 1;             // 0..1
    const int rowBase = blockIdx.x * 128;

    int mode, colBase;
    if (MODE_BASE == 3) { mode = 3; colBase = blockIdx.y * 128; }
    else { mode = blockIdx.y >> 2; colBase = (blockIdx.y & 3) * 128; }

    const ushort* __restrict__ W =
        (mode == 0) ? wq : (mode == 1) ? wk : (mode == 2) ? wv : wo;
    const float* __restrict__ bias =
        (mode == 0) ? bq : (mode == 1) ? bk : (mode == 2) ? bv : bo;

    const int fr = lane & 15;
    const int g = lane >> 4;
    const int fr7 = fr & 7;
    const int sc_row = tid >> 3;        // 0..31
    const int sc_c16 = tid & 7;

    f32x4 acc[4][4];
#pragma unroll
    for (int m = 0; m < 4; ++m)
#pragma unroll
        for (int n = 0; n < 4; ++n)
            acc[m][n] = (f32x4){0.f, 0.f, 0.f, 0.f};

    auto STAGE = [&](int kt) {
        const int k0 = kt * 64;
        const int bufb = (kt & 1) * 16384;
#pragma unroll
        for (int i = 0; i < 4; ++i) {
            const int row = i * 32 + sc_row;
            const int srcc = (sc_c16 ^ (row & 7)) * 8;
            GLD16(&A[(size_t)(rowBase + row) * E_DIM + k0 + srcc],
                  &SH[bufb + row * 64 + sc_c16 * 8]);
        }
#pragma unroll
        for (int i = 0; i < 4; ++i) {
            const int row = i * 32 + sc_row;
            const int srcc = (sc_c16 ^ (row & 7)) * 8;
            GLD16(&W[(size_t)(colBase + row) * E_DIM + k0 + srcc],
                  &SH[bufb + 8192 + row * 64 + sc_c16 * 8]);
        }
    };

    STAGE(0);
    STAGE(1);
    asm volatile("s_waitcnt vmcnt(8)" ::: "memory");
    __builtin_amdgcn_sched_barrier(0);
    __builtin_amdgcn_s_barrier();
    __builtin_amdgcn_sched_barrier(0);

    const int kch0 = (g ^ fr7) * 8;
    const int kch1 = ((4 + g) ^ fr7) * 8;
    const int aroff = (wm * 64 + fr) * 64;
    const int broff = 8192 + (wn * 64 + fr) * 64;
    const int b = rowBase >> 12;
    const int lloc = rowBase & (L_SEQ - 1);

    for (int gt = 0; gt < 8; ++gt) {
        const int base = (gt & 1) * 16384;
        bf16x8 af[2][4], bfv[2][4];
#pragma unroll
        for (int m = 0; m < 4; ++m) {
            af[0][m] = *reinterpret_cast<const bf16x8*>(&SH[base + aroff + m * 1024 + kch0]);
            af[1][m] = *reinterpret_cast<const bf16x8*>(&SH[base + aroff + m * 1024 + kch1]);
        }
#pragma unroll
        for (int n = 0; n < 4; ++n) {
            bfv[0][n] = *reinterpret_cast<const bf16x8*>(&SH[base + broff + n * 1024 + kch0]);
            bfv[1][n] = *reinterpret_cast<const bf16x8*>(&SH[base + broff + n * 1024 + kch1]);
        }
        BAR_LGKM();

        if (gt + 2 < 8) STAGE(gt + 2);

        __builtin_amdgcn_s_setprio(1);
#pragma unroll
        for (int kk = 0; kk < 2; ++kk)
#pragma unroll
            for (int m = 0; m < 4; ++m)
#pragma unroll
                for (int n = 0; n < 4; ++n)
                    acc[m][n] = __builtin_amdgcn_mfma_f32_16x16x32_bf16(
                        af[kk][m], bfv[kk][n], acc[m][n], 0, 0, 0);
        __builtin_amdgcn_s_setprio(0);
        __builtin_amdgcn_sched_barrier(0);

        if (gt < 7) {
            if (gt + 2 < 8) asm volatile("s_waitcnt vmcnt(8)" ::: "memory");
            else            asm volatile("s_waitcnt vmcnt(0)" ::: "memory");
            __builtin_amdgcn_sched_barrier(0);
            __builtin_amdgcn_s_barrier();
            __builtin_amdgcn_sched_barrier(0);
        }
    }

    // ---------------- epilogues ----------------
    if (mode == 0) {
#pragma unroll
        for (int m = 0; m < 4; ++m)
#pragma unroll
            for (int j = 0; j < 4; ++j) {
                const int grow = rowBase + wm * 64 + m * 16 + g * 4 + j;
#pragma unroll
                for (int n = 0; n < 4; ++n) {
                    const int gcol = colBase + wn * 64 + n * 16 + fr;
                    const float val = fmaxf(acc[m][n][j] + bias[gcol], 0.f);
                    qb[(size_t)grow * E_DIM + gcol] = f2bf(val);
                }
            }
    } else if (mode == 3) {
#pragma unroll
        for (int m = 0; m < 4; ++m)
#pragma unroll
            for (int j = 0; j < 4; ++j) {
                const int grow = rowBase + wm * 64 + m * 16 + g * 4 + j;
#pragma unroll
                for (int n = 0; n < 4; ++n) {
                    const int gcol = colBase + wn * 64 + n * 16 + fr;
                    outF[(size_t)grow * E_DIM + gcol] = acc[m][n][j] + bias[gcol];
                }
            }
    } else {
        ushort* __restrict__ dstbuf = (mode == 1) ? kT : vT;
        __syncthreads();                 // all waves done with SH buffers
        // scatter transposed into TS[feat 0..127][l 0..127], stride 136
#pragma unroll
        for (int m = 0; m < 4; ++m)
#pragma unroll
            for (int j = 0; j < 4; ++j) {
                const int lr_ = wm * 64 + m * 16 + g * 4 + j;
#pragma unroll
                for (int n = 0; n < 4; ++n) {
                    const int fcl = wn * 64 + n * 16 + fr;
                    float val = acc[m][n][j] + bias[colBase + fcl];
                    if (mode == 1) val = fmaxf(val, 0.f);
                    TS[fcl * 136 + lr_] = f2bf(val);
                }
            }
        __syncthreads();
#pragma unroll
        for (int i = 0; i < 8; ++i) {
            const int c = i * 256 + tid;
            const int r = c >> 4;              // local feature 0..127
            const int cc = c & 15;             // 16B chunk along l
            const size_t dst = ((size_t)(b * E_DIM + colBase + r)) * L_SEQ + lloc + cc * 8;
            *reinterpret_cast<uint4*>(&dstbuf[dst]) =
                *reinterpret_cast<const uint4*>(&TS[r * 136 + cc * 8]);
        }
    }
}

// ---------------- kv via MFMA, fused cos/sin from tables, no LDS ----------------
__global__ __launch_bounds__(256) void kv_kernel(
    const ushort* __restrict__ kT, const ushort* __restrict__ vT,
    const float* __restrict__ sintab, const float* __restrict__ costab,
    float* __restrict__ kv_part, float* __restrict__ sum_part)
{
    const int chunk = blockIdx.x;   // 0..7
    const int bh = blockIdx.y;      // 0..31
    const int tid = threadIdx.x;
    const int lane = tid & 63;
    const int w = tid >> 6;
    const int fr = lane & 15;
    const int g = lane >> 4;

    const size_t tbase = (size_t)bh * 64 * L_SEQ;

    f32x4 acc[8], accS[8];
#pragma unroll
    for (int n = 0; n < 8; ++n) {
        acc[n] = (f32x4){0.f, 0.f, 0.f, 0.f};
        accS[n] = (f32x4){0.f, 0.f, 0.f, 0.f};
    }

    const int lchunk = chunk * (L_SEQ / 8);
    for (int l0 = lchunk; l0 < lchunk + (L_SEQ / 8); l0 += 32) {
        const int col = l0 + g * 8;
        bf16x8 vf = *reinterpret_cast<const bf16x8*>(&vT[tbase + (size_t)(w * 16 + fr) * L_SEQ + col]);
        bf16x8 kf[4];
#pragma unroll
        for (int n = 0; n < 4; ++n)
            kf[n] = *reinterpret_cast<const bf16x8*>(&kT[tbase + (size_t)(n * 16 + fr) * L_SEQ + col]);
        float4 c0 = *reinterpret_cast<const float4*>(&costab[col]);
        float4 c1 = *reinterpret_cast<const float4*>(&costab[col + 4]);
        float4 s0 = *reinterpret_cast<const float4*>(&sintab[col]);
        float4 s1 = *reinterpret_cast<const float4*>(&sintab[col + 4]);
        const float c8[8] = {c0.x, c0.y, c0.z, c0.w, c1.x, c1.y, c1.z, c1.w};
        const float s8[8] = {s0.x, s0.y, s0.z, s0.w, s1.x, s1.y, s1.z, s1.w};
        bf16x8 afc, afs, cw, sw;
#pragma unroll
        for (int e = 0; e < 8; ++e) {
            const float v = bf2f((ushort)vf[e]);
            afc[e] = (short)f2bf(v * c8[e]);
            afs[e] = (short)f2bf(v * s8[e]);
            cw[e]  = (short)f2bf(c8[e]);
            sw[e]  = (short)f2bf(s8[e]);
        }
#pragma unroll
        for (int n = 0; n < 4; ++n) {
            acc[n]      = __builtin_amdgcn_mfma_f32_16x16x32_bf16(afc, kf[n], acc[n], 0, 0, 0);
            acc[n + 4]  = __builtin_amdgcn_mfma_f32_16x16x32_bf16(afs, kf[n], acc[n + 4], 0, 0, 0);
            accS[n]     = __builtin_amdgcn_mfma_f32_16x16x32_bf16(cw,  kf[n], accS[n], 0, 0, 0);
            accS[n + 4] = __builtin_amdgcn_mfma_f32_16x16x32_bf16(sw,  kf[n], accS[n + 4], 0, 0, 0);
        }
    }

    const size_t pbase = ((size_t)(chunk * 32 + bh)) * 8192;
#pragma unroll
    for (int n = 0; n < 8; ++n)
#pragma unroll
        for (int j = 0; j < 4; ++j)
            kv_part[pbase + (size_t)(w * 16 + g * 4 + j) * 128 + n * 16 + fr] = acc[n][j];
    if (w == 0 && g == 0) {
        const size_t sbase = (size_t)(chunk * 32 + bh) * 128;
#pragma unroll
        for (int n = 0; n < 8; ++n)
            sum_part[sbase + n * 16 + fr] = accS[n][0];
    }
}

// ---------------- reduce partials; emit bf16 kvT_ext[bh][80][128] ----------------
#define KVT_ROWS 80
#define KVT_STRIDE (KVT_ROWS * 128)
__global__ __launch_bounds__(256) void kv_reduce_kernel(
    const float* __restrict__ kv_part, const float* __restrict__ sum_part,
    ushort* __restrict__ kvT)
{
    const int bh = blockIdx.x;
    const int tid = threadIdx.x;
    ushort* kvb = kvT + (size_t)bh * KVT_STRIDE;
    for (int idx = tid; idx < 8192; idx += 256) {
        float s = 0.f;
#pragma unroll
        for (int c = 0; c < 8; ++c)
            s += kv_part[((size_t)(c * 32 + bh)) * 8192 + idx];
        kvb[idx] = f2bf(s);
    }
    if (tid < 128) {
        float s = 0.f;
#pragma unroll
        for (int c = 0; c < 8; ++c)
            s += sum_part[(size_t)(c * 32 + bh) * 128 + tid];
        const ushort hi = f2bf(s);
        const float lo = s - bf2f(hi);
        kvb[64 * 128 + tid] = hi;
        kvb[65 * 128 + tid] = f2bf(lo);
    }
    for (int idx = tid; idx < 14 * 128; idx += 256)
        kvb[66 * 128 + idx] = 0;
}

// ---------------- attention via MFMA: A-fragments scaled by cos/sin on the fly -------
__global__ __launch_bounds__(256) void attn_kernel(
    const ushort* __restrict__ Qb, const ushort* __restrict__ kvT,
    const float* __restrict__ sintab, const float* __restrict__ costab,
    ushort* __restrict__ attn_out)
{
    const int bh = blockIdx.y;
    const int b = bh >> 3, h = bh & 7;
    const int tid = threadIdx.x;
    const int lane = tid & 63;
    const int w = tid >> 6;

    __shared__ ushort Bs[KVT_ROWS][136];

#pragma unroll
    for (int i = 0; i < 5; ++i) {
        const int c = i * 256 + tid;
        const int d = c >> 4, cc = c & 15;
        *reinterpret_cast<uint4*>(&Bs[d][cc * 8]) =
            *reinterpret_cast<const uint4*>(&kvT[(size_t)bh * KVT_STRIDE + (size_t)c * 8]);
    }
    __syncthreads();

    const int rowBase = blockIdx.x * 256 + w * 64;
    const int fr = lane & 15;
    const int g = lane >> 4;

    float cvm[4], svm[4];
#pragma unroll
    for (int m = 0; m < 4; ++m) {
        const int l = (rowBase + m * 16 + fr) & (L_SEQ - 1);
        cvm[m] = costab[l];
        svm[m] = sintab[l];
    }

    f32x4 acc[4][5];
#pragma unroll
    for (int m = 0; m < 4; ++m)
#pragma unroll
        for (int n = 0; n < 5; ++n)
            acc[m][n] = (f32x4){0.f, 0.f, 0.f, 0.f};

#pragma unroll
    for (int ks = 0; ks < 4; ++ks) {
        const int kk = (ks & 1) * 32 + g * 8;
        const int kcomb = ks * 32 + g * 8;

        bf16x8 af[4];
#pragma unroll
        for (int m = 0; m < 4; ++m) {
            const int r = rowBase + m * 16 + fr;
            bf16x8 qf = *reinterpret_cast<const bf16x8*>(
                &Qb[((size_t)(b * L_SEQ) + r) * E_DIM + h * DHEAD + kk]);
            const float sc = (ks < 2) ? cvm[m] : svm[m];
#pragma unroll
            for (int e = 0; e < 8; ++e)
                af[m][e] = (short)f2bf(bf2f((ushort)qf[e]) * sc);
        }

        bf16x8 bfr[5];
#pragma unroll
        for (int n = 0; n < 5; ++n)
            bfr[n] = *reinterpret_cast<const bf16x8*>(&Bs[n * 16 + fr][kcomb]);
#pragma unroll
        for (int m = 0; m < 4; ++m)
#pragma unroll
            for (int n = 0; n < 5; ++n)
                acc[m][n] = __builtin_amdgcn_mfma_f32_16x16x32_bf16(af[m], bfr[n], acc[m][n], 0, 0, 0);
    }

#pragma unroll
    for (int m = 0; m < 4; ++m) {
#pragma unroll
        for (int j = 0; j < 4; ++j) {
            const float den = __shfl(acc[m][4][j], g * 16 + 0) + __shfl(acc[m][4][j], g * 16 + 1);
            const float z = 1.f / fmaxf(den, 1e-6f);
            const int grow = rowBase + m * 16 + g * 4 + j;
            const size_t obase = ((size_t)(b * L_SEQ) + grow) * E_DIM + h * DHEAD;
#pragma unroll
            for (int n = 0; n < 4; ++n)
                attn_out[obase + n * 16 + fr] = f2bf(acc[m][n][j] * z);
        }
    }
}

// ---------------- launch ----------------
extern "C" void kernel_launch(void* const* d_in, const int* in_sizes, int n_in,
                              void* d_out, int out_size, void* d_ws, size_t ws_size,
                              hipStream_t stream) {
    const float* x  = (const float*)d_in[0];
    const float* Wq = (const float*)d_in[1];
    const float* bq = (const float*)d_in[2];
    const float* Wk = (const float*)d_in[3];
    const float* bk = (const float*)d_in[4];
    const float* Wv = (const float*)d_in[5];
    const float* bv = (const float*)d_in[6];
    const float* Wo = (const float*)d_in[7];
    const float* bo = (const float*)d_in[8];
    float* out = (float*)d_out;

    char* ws = (char*)d_ws;
    size_t off = 0;
    auto alloc = [&](size_t bytes) -> char* {
        char* p = ws + off;
        off += (bytes + 255) & ~(size_t)255;
        return p;
    };

    const size_t big = (size_t)NROWS * E_DIM * sizeof(ushort);   // 16.8 MB
    ushort* xb  = (ushort*)alloc(big);
    ushort* wqb = (ushort*)alloc(512 * 512 * sizeof(ushort));
    ushort* wkb = (ushort*)alloc(512 * 512 * sizeof(ushort));
    ushort* wvb = (ushort*)alloc(512 * 512 * sizeof(ushort));
    ushort* wob = (ushort*)alloc(512 * 512 * sizeof(ushort));
    ushort* qb  = (ushort*)alloc(big);   // relu(q), [l][e]
    ushort* kT  = (ushort*)alloc(big);   // relu(k) transposed [bh][k][l]
    ushort* vT  = (ushort*)alloc(big);   // v transposed [bh][d][l]
    float* kv_part  = (float*)alloc((size_t)8 * 32 * 8192 * sizeof(float));
    float* sum_part = (float*)alloc((size_t)8 * 32 * 128 * sizeof(float));
    ushort* kvT     = (ushort*)alloc((size_t)32 * KVT_STRIDE * sizeof(ushort));
    float* sintab   = (float*)alloc(L_SEQ * sizeof(float));
    float* costab   = (float*)alloc(L_SEQ * sizeof(float));
    ushort* attnb = kT;  // kT consumed by kv_kernel before attn_kernel writes

    convert_kernel<<<2048, 256, 0, stream>>>(x, xb, NROWS * E_DIM / 4);
    convert_w_kernel<<<dim3(256, 5), 256, 0, stream>>>(
        Wq, Wk, Wv, Wo, wqb, wkb, wvb, wob, sintab, costab);

    // QKV: mode-major grid (panel on x -> same-XCD L2 sharing), 1536 blocks,
    // 2 blocks/CU -> 3 exact rounds
    gemm6_kernel<0><<<dim3(128, 12), 256, 0, stream>>>(
        xb, wqb, wkb, wvb, wob, bq, bk, bv, bo, qb, kT, vT, nullptr);

    kv_kernel<<<dim3(8, 32), 256, 0, stream>>>(kT, vT, sintab, costab, kv_part, sum_part);
    kv_reduce_kernel<<<32, 256, 0, stream>>>(kv_part, sum_part, kvT);

    attn_kernel<<<dim3(16, 32), 256, 0, stream>>>(qb, kvT, sintab, costab, attnb);

    // out GEMM: 512 blocks = 1 round at 2 blocks/CU
    gemm6_kernel<3><<<dim3(128, 4), 256, 0, stream>>>(
        attnb, wqb, wkb, wvb, wob, bq, bk, bv, bo, nullptr, nullptr, nullptr, out);
}